// Round 1
// baseline (571.971 us; speedup 1.0000x reference)
//
#include <hip/hip_runtime.h>
#include <math.h>

#define T_TOKENS 16384
#define H_DIM    2880
#define E_EXP    128
#define TOPK     4
#define M_TILE   32
#define KH       32

// LDS paddings
#define SA_LD (M_TILE + 4)   // 36, mult of 4 so float4 reads stay 16B-aligned
#define SW_LD (E_EXP + 4)    // 132, mult of 4
#define SL_LD (E_EXP + 1)    // 129 (double array, scalar access only)

__global__ __launch_bounds__(256) void gpt_oss_router_f64acc(
    const float* __restrict__ A,     // [T, H] hidden_states
    const float* __restrict__ W,     // [E, H] weight
    const float* __restrict__ bias,  // [E]
    float* __restrict__ out)         // [T*4 scores][T*4 indices-as-float]
{
    __shared__ float  sA[KH][SA_LD];      // [kk][t]   4.6 KB
    __shared__ float  sW[KH][SW_LD];      // [kk][e]  16.9 KB
    __shared__ double sL[M_TILE][SL_LD];  // logits   33.0 KB

    const int tid    = threadIdx.x;
    const int t_base = blockIdx.x * M_TILE;

    // compute-phase micro-tile mapping: 32 expert-cols x 8 token-rows
    const int col = tid & 31;   // expert group -> experts e0..e0+3
    const int row = tid >> 5;   // token  group -> tokens  t0..t0+3
    const int e0  = col * 4;
    const int t0  = row * 4;

    // staging mapping: each thread loads one float4 of A, four float4 of W
    const int a_t = tid >> 3;        // 0..31  (token row of A tile / expert row group of W)
    const int a_c = (tid & 7) * 4;   // 0..28  (col within KH chunk)

    double acc[4][4];
#pragma unroll
    for (int j = 0; j < 4; ++j)
#pragma unroll
        for (int i = 0; i < 4; ++i) acc[j][i] = 0.0;

    for (int h0 = 0; h0 < H_DIM; h0 += KH) {
        // global loads (before barrier so they overlap the previous compute's tail)
        float4 av = *(const float4*)(A + (size_t)(t_base + a_t) * H_DIM + h0 + a_c);
        float4 wv[4];
#pragma unroll
        for (int r = 0; r < 4; ++r) {
            const int e = r * 32 + a_t;
            wv[r] = *(const float4*)(W + (size_t)e * H_DIM + h0 + a_c);
        }

        __syncthreads();   // previous chunk's readers done

        sA[a_c + 0][a_t] = av.x;
        sA[a_c + 1][a_t] = av.y;
        sA[a_c + 2][a_t] = av.z;
        sA[a_c + 3][a_t] = av.w;
#pragma unroll
        for (int r = 0; r < 4; ++r) {
            const int e = r * 32 + a_t;
            sW[a_c + 0][e] = wv[r].x;
            sW[a_c + 1][e] = wv[r].y;
            sW[a_c + 2][e] = wv[r].z;
            sW[a_c + 3][e] = wv[r].w;
        }

        __syncthreads();   // tile visible

#pragma unroll
        for (int kk = 0; kk < KH; ++kk) {
            const float4 af = *(const float4*)&sA[kk][t0];
            const float4 wf = *(const float4*)&sW[kk][e0];
            const double ad[4] = {(double)af.x, (double)af.y, (double)af.z, (double)af.w};
            const double wd[4] = {(double)wf.x, (double)wf.y, (double)wf.z, (double)wf.w};
#pragma unroll
            for (int j = 0; j < 4; ++j)
#pragma unroll
                for (int i = 0; i < 4; ++i)
                    acc[j][i] += ad[j] * wd[i];   // exact product, f64 accumulate
        }
    }

    __syncthreads();
    // park logits (+bias, in f64) in LDS
#pragma unroll
    for (int j = 0; j < 4; ++j)
#pragma unroll
        for (int i = 0; i < 4; ++i)
            sL[t0 + j][e0 + i] = acc[j][i] + (double)bias[e0 + i];

    __syncthreads();

    // top-4 (stable: strict '>' keeps the lower index first on ties) + softmax
    if (tid < M_TILE) {
        const int t = tid;
        double bv0 = -1e300, bv1 = -1e300, bv2 = -1e300, bv3 = -1e300;
        int    bi0 = 0, bi1 = 0, bi2 = 0, bi3 = 0;
        for (int e = 0; e < E_EXP; ++e) {
            const double v = sL[t][e];
            if (v > bv3) {
                if (v > bv0) {
                    bv3 = bv2; bi3 = bi2;
                    bv2 = bv1; bi2 = bi1;
                    bv1 = bv0; bi1 = bi0;
                    bv0 = v;   bi0 = e;
                } else if (v > bv1) {
                    bv3 = bv2; bi3 = bi2;
                    bv2 = bv1; bi2 = bi1;
                    bv1 = v;   bi1 = e;
                } else if (v > bv2) {
                    bv3 = bv2; bi3 = bi2;
                    bv2 = v;   bi2 = e;
                } else {
                    bv3 = v;   bi3 = e;
                }
            }
        }
        const double m  = bv0;
        const double e0x = exp(bv0 - m);
        const double e1x = exp(bv1 - m);
        const double e2x = exp(bv2 - m);
        const double e3x = exp(bv3 - m);
        const double s  = e0x + e1x + e2x + e3x;

        const int gt = t_base + t;
        float* out_scores = out;
        float* out_idx    = out + (size_t)T_TOKENS * TOPK;
        out_scores[gt * 4 + 0] = (float)(e0x / s);
        out_scores[gt * 4 + 1] = (float)(e1x / s);
        out_scores[gt * 4 + 2] = (float)(e2x / s);
        out_scores[gt * 4 + 3] = (float)(e3x / s);
        out_idx[gt * 4 + 0] = (float)bi0;
        out_idx[gt * 4 + 1] = (float)bi1;
        out_idx[gt * 4 + 2] = (float)bi2;
        out_idx[gt * 4 + 3] = (float)bi3;
    }
}

extern "C" void kernel_launch(void* const* d_in, const int* in_sizes, int n_in,
                              void* d_out, int out_size, void* d_ws, size_t ws_size,
                              hipStream_t stream) {
    const float* A    = (const float*)d_in[0];
    const float* W    = (const float*)d_in[1];
    const float* bias = (const float*)d_in[2];
    float* out = (float*)d_out;

    dim3 grid(T_TOKENS / M_TILE);   // 512
    dim3 block(256);
    gpt_oss_router_f64acc<<<grid, block, 0, stream>>>(A, W, bias, out);
}

// Round 3
// 419.156 us; speedup vs baseline: 1.3646x; 1.3646x over previous
//
#include <hip/hip_runtime.h>
#include <math.h>

#define T_TOKENS 16384
#define H_DIM    2880
#define E_EXP    128
#define TOPK     4
#define MT       32        // tokens per block (main kernel)
#define KC       32        // K chunk per iteration
#define EPS_GAP  5e-4f     // gap threshold: ~10x the bf16x3 logit error tail

typedef __bf16 bf16x8 __attribute__((ext_vector_type(8)));
typedef float  f32x4  __attribute__((ext_vector_type(4)));

__device__ __forceinline__ unsigned short bf16_rn(float x) {
    unsigned int u = __float_as_uint(x);
    unsigned int r = (u + 0x7fffu + ((u >> 16) & 1u)) >> 16;
    return (unsigned short)r;
}
__device__ __forceinline__ float bf16_tof(unsigned short h) {
    return __uint_as_float(((unsigned int)h) << 16);
}
__device__ __forceinline__ unsigned int pack2(unsigned short a, unsigned short b) {
    return (unsigned int)a | ((unsigned int)b << 16);
}

// ---------------------------------------------------------------------------
// Main kernel: bf16x3 MFMA GEMM (16x16x32), fused bias + top-5 + softmax.
// Block = 32 tokens x 128 experts, 256 threads (4 waves), grid 512.
// Wave w: m-tile = w&1 (16 tokens), n-half = w>>1 (4 n-tiles of 16 experts).
// LDS fragment-major layout: within each tile region, lane L's 16B MFMA
// fragment lives at byte offset L*16 (conflict-free b128 reads).
// ---------------------------------------------------------------------------
__global__ __launch_bounds__(256, 2) void router_main(
    const float* __restrict__ A, const float* __restrict__ W,
    const float* __restrict__ bias, float* __restrict__ out,
    int* __restrict__ flag_count, int* __restrict__ flag_list)
{
    __shared__ __align__(16) uint2 sAhi[2][128];   // 2 m-tiles * 64 chunks * 16B
    __shared__ __align__(16) uint2 sAlo[2][128];
    __shared__ __align__(16) uint4 sWhi[8][64];    // 8 n-tiles * 64 chunks * 16B
    __shared__ __align__(16) uint4 sWlo[8][64];
    __shared__ float sL[MT][129];                  // logits, +1 pad

    const int tid    = threadIdx.x;
    const int t_base = blockIdx.x * MT;

    const int wave = tid >> 6;
    const int L    = tid & 63;
    const int wm   = wave & 1;    // m-tile index
    const int wn   = wave >> 1;   // n-half index

    // --- staging maps ---
    // A: thread loads A[t_base+at][k0 + ac*4 .. +3]  (float4)
    const int at = tid >> 3;       // 0..31
    const int ac = tid & 7;        // 0..7
    const int a_idx = (at >> 4) * 128 + ((((ac >> 1) << 4) | (at & 15)) << 1) + (ac & 1);
    const float* Ag = A + (size_t)(t_base + at) * H_DIM + ac * 4;
    // W: thread loads W[we][k0 + wq0*8 .. +15] (two adjacent 8-float k-chunks)
    const int we  = tid >> 1;      // 0..127
    const int wq0 = (tid & 1) * 2; // 0 or 2
    const float* Wg = W + (size_t)we * H_DIM + wq0 * 8;
    const int w_nt = we >> 4;
    const int w_n  = we & 15;

    f32x4 acc[4];
#pragma unroll
    for (int i = 0; i < 4; ++i) { f32x4 z = {0.f, 0.f, 0.f, 0.f}; acc[i] = z; }

    uint2* sAhiF = &sAhi[0][0];
    uint2* sAloF = &sAlo[0][0];

    for (int k0 = 0; k0 < H_DIM; k0 += KC) {
        // global loads (pre-barrier, overlap previous compute tail)
        const float4 av  = *(const float4*)(Ag + k0);
        const float4 wv0 = *(const float4*)(Wg + k0);        // chunk wq0,   k rel 0..3
        const float4 wv1 = *(const float4*)(Wg + k0 + 4);    // chunk wq0,   k rel 4..7
        const float4 wv2 = *(const float4*)(Wg + k0 + 8);    // chunk wq0+1, k rel 0..3
        const float4 wv3 = *(const float4*)(Wg + k0 + 12);   // chunk wq0+1, k rel 4..7

        // convert A -> hi/lo bf16
        float af[4] = {av.x, av.y, av.z, av.w};
        unsigned short ah[4], al[4];
#pragma unroll
        for (int j = 0; j < 4; ++j) {
            ah[j] = bf16_rn(af[j]);
            al[j] = bf16_rn(af[j] - bf16_tof(ah[j]));
        }
        const uint2 ahp = make_uint2(pack2(ah[0], ah[1]), pack2(ah[2], ah[3]));
        const uint2 alp = make_uint2(pack2(al[0], al[1]), pack2(al[2], al[3]));

        // convert W -> hi/lo bf16
        float wf[16] = {wv0.x, wv0.y, wv0.z, wv0.w, wv1.x, wv1.y, wv1.z, wv1.w,
                        wv2.x, wv2.y, wv2.z, wv2.w, wv3.x, wv3.y, wv3.z, wv3.w};
        unsigned short wh[16], wl[16];
#pragma unroll
        for (int j = 0; j < 16; ++j) {
            wh[j] = bf16_rn(wf[j]);
            wl[j] = bf16_rn(wf[j] - bf16_tof(wh[j]));
        }
        const uint4 whp0 = make_uint4(pack2(wh[0], wh[1]), pack2(wh[2], wh[3]),
                                      pack2(wh[4], wh[5]), pack2(wh[6], wh[7]));
        const uint4 whp1 = make_uint4(pack2(wh[8], wh[9]), pack2(wh[10], wh[11]),
                                      pack2(wh[12], wh[13]), pack2(wh[14], wh[15]));
        const uint4 wlp0 = make_uint4(pack2(wl[0], wl[1]), pack2(wl[2], wl[3]),
                                      pack2(wl[4], wl[5]), pack2(wl[6], wl[7]));
        const uint4 wlp1 = make_uint4(pack2(wl[8], wl[9]), pack2(wl[10], wl[11]),
                                      pack2(wl[12], wl[13]), pack2(wl[14], wl[15]));

        __syncthreads();   // previous iteration's fragment reads complete

        sAhiF[a_idx] = ahp;
        sAloF[a_idx] = alp;
        sWhi[w_nt][((wq0 + 0) << 4) | w_n] = whp0;
        sWhi[w_nt][((wq0 + 1) << 4) | w_n] = whp1;
        sWlo[w_nt][((wq0 + 0) << 4) | w_n] = wlp0;
        sWlo[w_nt][((wq0 + 1) << 4) | w_n] = wlp1;

        __syncthreads();   // tile visible

        const bf16x8 ahi = *(const bf16x8*)&sAhi[wm][L * 2];
        const bf16x8 alo = *(const bf16x8*)&sAlo[wm][L * 2];
#pragma unroll
        for (int i = 0; i < 4; ++i) {
            const int nt = wn * 4 + i;
            const bf16x8 whi = *(const bf16x8*)&sWhi[nt][L];
            const bf16x8 wlo = *(const bf16x8*)&sWlo[nt][L];
            acc[i] = __builtin_amdgcn_mfma_f32_16x16x32_bf16(ahi, whi, acc[i], 0, 0, 0);
            acc[i] = __builtin_amdgcn_mfma_f32_16x16x32_bf16(ahi, wlo, acc[i], 0, 0, 0);
            acc[i] = __builtin_amdgcn_mfma_f32_16x16x32_bf16(alo, whi, acc[i], 0, 0, 0);
        }
    }

    // epilogue: C/D layout col(expert)=lane&15, row(token)=(lane>>4)*4+reg
#pragma unroll
    for (int i = 0; i < 4; ++i) {
        const int e = wn * 64 + i * 16 + (L & 15);
        const float b = bias[e];
#pragma unroll
        for (int r = 0; r < 4; ++r) {
            const int tl = wm * 16 + (L >> 4) * 4 + r;
            sL[tl][e] = acc[i][r] + b;
        }
    }
    __syncthreads();

    // top-5 scan (stable: strict '>' keeps lowest index on ties) + gap test + softmax
    if (tid < MT) {
        float v0 = -1e30f, v1 = -1e30f, v2 = -1e30f, v3 = -1e30f, v4 = -1e30f;
        int   i0 = 0, i1 = 0, i2 = 0, i3 = 0, i4 = 0;
        for (int e = 0; e < E_EXP; ++e) {
            const float x = sL[tid][e];
            if (x > v4) {
                if (x > v0)      { v4=v3;i4=i3; v3=v2;i3=i2; v2=v1;i2=i1; v1=v0;i1=i0; v0=x;i0=e; }
                else if (x > v1) { v4=v3;i4=i3; v3=v2;i3=i2; v2=v1;i2=i1; v1=x;i1=e; }
                else if (x > v2) { v4=v3;i4=i3; v3=v2;i3=i2; v2=x;i2=e; }
                else if (x > v3) { v4=v3;i4=i3; v3=x;i3=e; }
                else             { v4=x;i4=e; }
            }
        }
        const float g0 = v0 - v1, g1 = v1 - v2, g2 = v2 - v3, g3 = v3 - v4;
        float mg = g0 < g1 ? g0 : g1;
        mg = mg < g2 ? mg : g2;
        mg = mg < g3 ? mg : g3;

        const float e0x = expf(v0 - v0);
        const float e1x = expf(v1 - v0);
        const float e2x = expf(v2 - v0);
        const float e3x = expf(v3 - v0);
        const float s   = e0x + e1x + e2x + e3x;

        const int gt = t_base + tid;
        float* out_scores = out;
        float* out_idx    = out + (size_t)T_TOKENS * TOPK;
        out_scores[gt * 4 + 0] = e0x / s;
        out_scores[gt * 4 + 1] = e1x / s;
        out_scores[gt * 4 + 2] = e2x / s;
        out_scores[gt * 4 + 3] = e3x / s;
        out_idx[gt * 4 + 0] = (float)i0;
        out_idx[gt * 4 + 1] = (float)i1;
        out_idx[gt * 4 + 2] = (float)i2;
        out_idx[gt * 4 + 3] = (float)i3;

        if (mg < EPS_GAP) {
            const int p = atomicAdd(flag_count, 1);
            if (p < T_TOKENS) flag_list[p] = gt;
        }
    }
}

// ---------------------------------------------------------------------------
// Recheck kernel: exact f64 recompute of flagged tokens (round-1-verified
// semantics: f64 dot, strict-> stable top-4, f64 softmax).
// ---------------------------------------------------------------------------
__global__ __launch_bounds__(256) void router_recheck(
    const float* __restrict__ A, const float* __restrict__ W,
    const float* __restrict__ bias, float* __restrict__ out,
    const int* __restrict__ flag_count, const int* __restrict__ flag_list)
{
    __shared__ double sPart[256];
    __shared__ double sLog[E_EXP];

    int count = *flag_count;
    if (count > T_TOKENS) count = T_TOKENS;

    const int tid = threadIdx.x;
    const int e   = tid & (E_EXP - 1);
    const int h   = tid >> 7;          // K half: 0 or 1

    for (int i = blockIdx.x; i < count; i += gridDim.x) {
        const int t = flag_list[i];
        const float* arow = A + (size_t)t * H_DIM;
        const float* wrow = W + (size_t)e * H_DIM;
        const int k0 = h * (H_DIM / 2);

        double s0 = 0.0, s1 = 0.0, s2 = 0.0, s3 = 0.0;
        for (int k = k0; k < k0 + H_DIM / 2; k += 4) {
            s0 += (double)arow[k + 0] * (double)wrow[k + 0];
            s1 += (double)arow[k + 1] * (double)wrow[k + 1];
            s2 += (double)arow[k + 2] * (double)wrow[k + 2];
            s3 += (double)arow[k + 3] * (double)wrow[k + 3];
        }
        sPart[tid] = (s0 + s1) + (s2 + s3);
        __syncthreads();
        if (h == 0) sLog[e] = sPart[e] + sPart[e + 128] + (double)bias[e];
        __syncthreads();

        if (tid == 0) {
            double v0 = -1e300, v1 = -1e300, v2 = -1e300, v3 = -1e300;
            int    i0 = 0, i1 = 0, i2 = 0, i3 = 0;
            for (int q = 0; q < E_EXP; ++q) {
                const double x = sLog[q];
                if (x > v3) {
                    if (x > v0)      { v3=v2;i3=i2; v2=v1;i2=i1; v1=v0;i1=i0; v0=x;i0=q; }
                    else if (x > v1) { v3=v2;i3=i2; v2=v1;i2=i1; v1=x;i1=q; }
                    else if (x > v2) { v3=v2;i3=i2; v2=x;i2=q; }
                    else             { v3=x;i3=q; }
                }
            }
            const double e0x = exp(v0 - v0);
            const double e1x = exp(v1 - v0);
            const double e2x = exp(v2 - v0);
            const double e3x = exp(v3 - v0);
            const double s   = e0x + e1x + e2x + e3x;
            float* out_scores = out;
            float* out_idx    = out + (size_t)T_TOKENS * TOPK;
            out_scores[t * 4 + 0] = (float)(e0x / s);
            out_scores[t * 4 + 1] = (float)(e1x / s);
            out_scores[t * 4 + 2] = (float)(e2x / s);
            out_scores[t * 4 + 3] = (float)(e3x / s);
            out_idx[t * 4 + 0] = (float)i0;
            out_idx[t * 4 + 1] = (float)i1;
            out_idx[t * 4 + 2] = (float)i2;
            out_idx[t * 4 + 3] = (float)i3;
        }
        __syncthreads();   // sPart/sLog reuse safety for next row
    }
}

extern "C" void kernel_launch(void* const* d_in, const int* in_sizes, int n_in,
                              void* d_out, int out_size, void* d_ws, size_t ws_size,
                              hipStream_t stream) {
    const float* A    = (const float*)d_in[0];
    const float* W    = (const float*)d_in[1];
    const float* bias = (const float*)d_in[2];
    float* out = (float*)d_out;

    int* flag_count = (int*)d_ws;
    int* flag_list  = (int*)d_ws + 1;

    hipMemsetAsync(flag_count, 0, sizeof(int), stream);   // ws is re-poisoned each call
    router_main<<<dim3(T_TOKENS / MT), dim3(256), 0, stream>>>(A, W, bias, out,
                                                               flag_count, flag_list);
    router_recheck<<<dim3(256), dim3(256), 0, stream>>>(A, W, bias, out,
                                                        flag_count, flag_list);
}

// Round 4
// 392.032 us; speedup vs baseline: 1.4590x; 1.0692x over previous
//
#include <hip/hip_runtime.h>
#include <hip/hip_bf16.h>
#include <math.h>

#define T_TOKENS 16384
#define H_DIM    2880
#define KHALF    1440      // H_DIM/2, per in-block K-split half
#define E_EXP    128
#define TOPK     4
#define MT       32        // tokens per block
#define KC       32        // K chunk per iteration
#define EPS_GAP  5e-4f     // gap threshold: ~100x the bf16x3 logit error tail

typedef __bf16 bf16x8 __attribute__((ext_vector_type(8)));
typedef float  f32x4  __attribute__((ext_vector_type(4)));

// packed RNE split: (a,b) -> hi word [b_hi|a_hi], lo word [b_lo|a_lo]
__device__ __forceinline__ void split2(float a, float b,
                                       unsigned int& hi, unsigned int& lo) {
    float2 p; p.x = a; p.y = b;
    __hip_bfloat162 h = __float22bfloat162_rn(p);
    unsigned int hu; __builtin_memcpy(&hu, &h, 4);
    float2 r;
    r.x = a - __uint_as_float((hu & 0xffffu) << 16);
    r.y = b - __uint_as_float(hu & 0xffff0000u);
    __hip_bfloat162 l = __float22bfloat162_rn(r);
    unsigned int lu; __builtin_memcpy(&lu, &l, 4);
    hi = hu; lo = lu;
}

// ---------------------------------------------------------------------------
// Main kernel: bf16x3 MFMA GEMM (16x16x32), in-block split-K (2 halves),
// fused bias + top-5 + gap-test + softmax.
// Block = 512 threads (8 waves) x 32 tokens x 128 experts; grid 512.
// Waves 0-3: K in [0,1440); waves 4-7: K in [1440,2880). Within a half:
// wm = wave&1 (m-tile), wn = (wave>>1)&1 (n-half of 4 n-tiles).
// LDS fragment-major: lane L's 16B MFMA fragment at byte offset L*16.
// ---------------------------------------------------------------------------
__global__ __launch_bounds__(512, 4) void router_main(
    const float* __restrict__ A, const float* __restrict__ W,
    const float* __restrict__ bias, float* __restrict__ out,
    int* __restrict__ flag_count, int* __restrict__ flag_list)
{
    __shared__ __align__(16) uint2 sAhi[2][2][128];   // [half][m-tile][frag]  4 KB
    __shared__ __align__(16) uint2 sAlo[2][2][128];   //                       4 KB
    __shared__ __align__(16) uint4 sWhi[2][8][64];    // [half][n-tile][frag] 16 KB
    __shared__ __align__(16) uint4 sWlo[2][8][64];    //                      16 KB
    __shared__ float sL[MT][129];                     // logits, +1 pad      16.5 KB

    const int tid    = threadIdx.x;
    const int t_base = blockIdx.x * MT;

    const int wave  = tid >> 6;
    const int L     = tid & 63;
    const int whalf = wave >> 2;        // K half this wave computes
    const int wm    = wave & 1;         // m-tile
    const int wn    = (wave >> 1) & 1;  // n-half (4 n-tiles)

    // --- staging maps (per half: threads tid_h = tid&255, half = tid>>8) ---
    const int shalf = tid >> 8;
    const int tid_h = tid & 255;
    const int at = tid_h >> 3;       // 0..31 token
    const int ac = tid_h & 7;        // 0..7  k-quad
    const int a_idx = (at >> 4) * 128 + ((((ac >> 1) << 4) | (at & 15)) << 1) + (ac & 1);
    const float* Ag = A + (size_t)(t_base + at) * H_DIM + shalf * KHALF + ac * 4;
    const int we  = tid_h >> 1;      // 0..127 expert
    const int wq0 = (tid_h & 1) * 2; // 0 or 2
    const float* Wg = W + (size_t)we * H_DIM + shalf * KHALF + wq0 * 8;
    const int w_nt = we >> 4;
    const int w_n  = we & 15;

    uint2* sAhiF = &sAhi[shalf][0][0];
    uint2* sAloF = &sAlo[shalf][0][0];

    f32x4 acc[4];
#pragma unroll
    for (int i = 0; i < 4; ++i) { f32x4 z = {0.f, 0.f, 0.f, 0.f}; acc[i] = z; }

    for (int k0 = 0; k0 < KHALF; k0 += KC) {
        // global loads (pre-barrier, overlap previous compute tail)
        const float4 av  = *(const float4*)(Ag + k0);
        const float4 wv0 = *(const float4*)(Wg + k0);        // chunk wq0,   k 0..3
        const float4 wv1 = *(const float4*)(Wg + k0 + 4);    // chunk wq0,   k 4..7
        const float4 wv2 = *(const float4*)(Wg + k0 + 8);    // chunk wq0+1, k 0..3
        const float4 wv3 = *(const float4*)(Wg + k0 + 12);   // chunk wq0+1, k 4..7

        uint2 ahp, alp;
        split2(av.x, av.y, ahp.x, alp.x);
        split2(av.z, av.w, ahp.y, alp.y);

        uint4 whp0, wlp0, whp1, wlp1;
        split2(wv0.x, wv0.y, whp0.x, wlp0.x);
        split2(wv0.z, wv0.w, whp0.y, wlp0.y);
        split2(wv1.x, wv1.y, whp0.z, wlp0.z);
        split2(wv1.z, wv1.w, whp0.w, wlp0.w);
        split2(wv2.x, wv2.y, whp1.x, wlp1.x);
        split2(wv2.z, wv2.w, whp1.y, wlp1.y);
        split2(wv3.x, wv3.y, whp1.z, wlp1.z);
        split2(wv3.z, wv3.w, whp1.w, wlp1.w);

        __syncthreads();   // previous iteration's fragment reads complete

        sAhiF[a_idx] = ahp;
        sAloF[a_idx] = alp;
        sWhi[shalf][w_nt][((wq0 + 0) << 4) | w_n] = whp0;
        sWhi[shalf][w_nt][((wq0 + 1) << 4) | w_n] = whp1;
        sWlo[shalf][w_nt][((wq0 + 0) << 4) | w_n] = wlp0;
        sWlo[shalf][w_nt][((wq0 + 1) << 4) | w_n] = wlp1;

        __syncthreads();   // tile visible

        const bf16x8 ahi = *(const bf16x8*)&sAhi[whalf][wm][L * 2];
        const bf16x8 alo = *(const bf16x8*)&sAlo[whalf][wm][L * 2];
#pragma unroll
        for (int i = 0; i < 4; ++i) {
            const int nt = wn * 4 + i;
            const bf16x8 whi = *(const bf16x8*)&sWhi[whalf][nt][L];
            const bf16x8 wlo = *(const bf16x8*)&sWlo[whalf][nt][L];
            acc[i] = __builtin_amdgcn_mfma_f32_16x16x32_bf16(ahi, whi, acc[i], 0, 0, 0);
            acc[i] = __builtin_amdgcn_mfma_f32_16x16x32_bf16(ahi, wlo, acc[i], 0, 0, 0);
            acc[i] = __builtin_amdgcn_mfma_f32_16x16x32_bf16(alo, whi, acc[i], 0, 0, 0);
        }
    }

    // epilogue: C/D layout col(expert)=lane&15, row(token)=(lane>>4)*4+reg
    // half 0 writes (+bias); half 1 accumulates.
    __syncthreads();
    if (whalf == 0) {
#pragma unroll
        for (int i = 0; i < 4; ++i) {
            const int e = wn * 64 + i * 16 + (L & 15);
            const float b = bias[e];
#pragma unroll
            for (int r = 0; r < 4; ++r)
                sL[wm * 16 + (L >> 4) * 4 + r][e] = acc[i][r] + b;
        }
    }
    __syncthreads();
    if (whalf == 1) {
#pragma unroll
        for (int i = 0; i < 4; ++i) {
            const int e = wn * 64 + i * 16 + (L & 15);
#pragma unroll
            for (int r = 0; r < 4; ++r)
                sL[wm * 16 + (L >> 4) * 4 + r][e] += acc[i][r];
        }
    }
    __syncthreads();

    // top-5 scan (stable: strict '>' keeps lowest index on ties) + gap test + softmax
    if (tid < MT) {
        float v0 = -1e30f, v1 = -1e30f, v2 = -1e30f, v3 = -1e30f, v4 = -1e30f;
        int   i0 = 0, i1 = 0, i2 = 0, i3 = 0, i4 = 0;
        for (int e = 0; e < E_EXP; ++e) {
            const float x = sL[tid][e];
            if (x > v4) {
                if (x > v0)      { v4=v3;i4=i3; v3=v2;i3=i2; v2=v1;i2=i1; v1=v0;i1=i0; v0=x;i0=e; }
                else if (x > v1) { v4=v3;i4=i3; v3=v2;i3=i2; v2=v1;i2=i1; v1=x;i1=e; }
                else if (x > v2) { v4=v3;i4=i3; v3=v2;i3=i2; v2=x;i2=e; }
                else if (x > v3) { v4=v3;i4=i3; v3=x;i3=e; }
                else             { v4=x;i4=e; }
            }
        }
        const float g0 = v0 - v1, g1 = v1 - v2, g2 = v2 - v3, g3 = v3 - v4;
        float mg = g0 < g1 ? g0 : g1;
        mg = mg < g2 ? mg : g2;
        mg = mg < g3 ? mg : g3;

        const float e0x = expf(v0 - v0);
        const float e1x = expf(v1 - v0);
        const float e2x = expf(v2 - v0);
        const float e3x = expf(v3 - v0);
        const float s   = e0x + e1x + e2x + e3x;

        const int gt = t_base + tid;
        float* out_scores = out;
        float* out_idx    = out + (size_t)T_TOKENS * TOPK;
        out_scores[gt * 4 + 0] = e0x / s;
        out_scores[gt * 4 + 1] = e1x / s;
        out_scores[gt * 4 + 2] = e2x / s;
        out_scores[gt * 4 + 3] = e3x / s;
        out_idx[gt * 4 + 0] = (float)i0;
        out_idx[gt * 4 + 1] = (float)i1;
        out_idx[gt * 4 + 2] = (float)i2;
        out_idx[gt * 4 + 3] = (float)i3;

        if (mg < EPS_GAP) {
            const int p = atomicAdd(flag_count, 1);
            if (p < T_TOKENS) flag_list[p] = gt;
        }
    }
}

// ---------------------------------------------------------------------------
// Recheck kernel: exact f64 recompute of flagged tokens (round-1-verified
// semantics: f64 dot in k%4 buckets, strict-> stable top-4, f64 softmax).
// float4 loads to cut latency exposure.
// ---------------------------------------------------------------------------
__global__ __launch_bounds__(256) void router_recheck(
    const float* __restrict__ A, const float* __restrict__ W,
    const float* __restrict__ bias, float* __restrict__ out,
    const int* __restrict__ flag_count, const int* __restrict__ flag_list)
{
    __shared__ double sPart[256];
    __shared__ double sLog[E_EXP];

    int count = *flag_count;
    if (count > T_TOKENS) count = T_TOKENS;

    const int tid = threadIdx.x;
    const int e   = tid & (E_EXP - 1);
    const int h   = tid >> 7;          // K half: 0 or 1

    for (int i = blockIdx.x; i < count; i += gridDim.x) {
        const int t = flag_list[i];
        const float* arow = A + (size_t)t * H_DIM;
        const float* wrow = W + (size_t)e * H_DIM;
        const int k0 = h * (H_DIM / 2);

        double s0 = 0.0, s1 = 0.0, s2 = 0.0, s3 = 0.0;
        for (int k = k0; k < k0 + H_DIM / 2; k += 8) {
            const float4 a0 = *(const float4*)(arow + k);
            const float4 a1 = *(const float4*)(arow + k + 4);
            const float4 w0 = *(const float4*)(wrow + k);
            const float4 w1 = *(const float4*)(wrow + k + 4);
            s0 += (double)a0.x * (double)w0.x;
            s1 += (double)a0.y * (double)w0.y;
            s2 += (double)a0.z * (double)w0.z;
            s3 += (double)a0.w * (double)w0.w;
            s0 += (double)a1.x * (double)w1.x;
            s1 += (double)a1.y * (double)w1.y;
            s2 += (double)a1.z * (double)w1.z;
            s3 += (double)a1.w * (double)w1.w;
        }
        sPart[tid] = (s0 + s1) + (s2 + s3);
        __syncthreads();
        if (h == 0) sLog[e] = sPart[e] + sPart[e + 128] + (double)bias[e];
        __syncthreads();

        if (tid == 0) {
            double v0 = -1e300, v1 = -1e300, v2 = -1e300, v3 = -1e300;
            int    i0 = 0, i1 = 0, i2 = 0, i3 = 0;
            for (int q = 0; q < E_EXP; ++q) {
                const double x = sLog[q];
                if (x > v3) {
                    if (x > v0)      { v3=v2;i3=i2; v2=v1;i2=i1; v1=v0;i1=i0; v0=x;i0=q; }
                    else if (x > v1) { v3=v2;i3=i2; v2=v1;i2=i1; v1=x;i1=q; }
                    else if (x > v2) { v3=v2;i3=i2; v2=x;i2=q; }
                    else             { v3=x;i3=q; }
                }
            }
            const double e0x = exp(v0 - v0);
            const double e1x = exp(v1 - v0);
            const double e2x = exp(v2 - v0);
            const double e3x = exp(v3 - v0);
            const double s   = e0x + e1x + e2x + e3x;
            float* out_scores = out;
            float* out_idx    = out + (size_t)T_TOKENS * TOPK;
            out_scores[t * 4 + 0] = (float)(e0x / s);
            out_scores[t * 4 + 1] = (float)(e1x / s);
            out_scores[t * 4 + 2] = (float)(e2x / s);
            out_scores[t * 4 + 3] = (float)(e3x / s);
            out_idx[t * 4 + 0] = (float)i0;
            out_idx[t * 4 + 1] = (float)i1;
            out_idx[t * 4 + 2] = (float)i2;
            out_idx[t * 4 + 3] = (float)i3;
        }
        __syncthreads();   // sPart/sLog reuse safety for next row
    }
}

extern "C" void kernel_launch(void* const* d_in, const int* in_sizes, int n_in,
                              void* d_out, int out_size, void* d_ws, size_t ws_size,
                              hipStream_t stream) {
    const float* A    = (const float*)d_in[0];
    const float* W    = (const float*)d_in[1];
    const float* bias = (const float*)d_in[2];
    float* out = (float*)d_out;

    int* flag_count = (int*)d_ws;
    int* flag_list  = (int*)d_ws + 1;

    hipMemsetAsync(flag_count, 0, sizeof(int), stream);   // ws is re-poisoned each call
    router_main<<<dim3(T_TOKENS / MT), dim3(512), 0, stream>>>(A, W, bias, out,
                                                               flag_count, flag_list);
    router_recheck<<<dim3(256), dim3(256), 0, stream>>>(A, W, bias, out,
                                                        flag_count, flag_list);
}

// Round 6
// 384.725 us; speedup vs baseline: 1.4867x; 1.0190x over previous
//
#include <hip/hip_runtime.h>
#include <hip/hip_bf16.h>
#include <math.h>

#define T_TOKENS 16384
#define H_DIM    2880
#define KHALF    1440      // H_DIM/2, per in-block K-split half
#define E_EXP    128
#define TOPK     4
#define MT       32        // tokens per block
#define KC       32        // K chunk per iteration
#define NCHUNK   (H_DIM / KC)          // 90
#define NCHUNK_H (KHALF / KC)          // 45
#define EPS_GAP  5e-4f     // gap threshold: ~10x the bf16x3 logit error tail

// d_ws layout (prep path):
//   [0..63]                : flag_count (int at offset 0) + pad
//   [64 .. 64+1.44MB)      : W frags, [chunk kc][hi:512 | lo:512 uint4]
//   [then]                 : flag_list (T_TOKENS ints)
#define WS_WOFF   64
#define WS_WBYTES (NCHUNK * 1024 * 16)
#define WS_FLOFF  (WS_WOFF + WS_WBYTES)
#define WS_NEED   (WS_FLOFF + T_TOKENS * 4)

typedef __bf16 bf16x8 __attribute__((ext_vector_type(8)));
typedef float  f32x4  __attribute__((ext_vector_type(4)));

// packed RNE split: (a,b) -> hi word [b_hi|a_hi], lo word [b_lo|a_lo]
__device__ __forceinline__ void split2(float a, float b,
                                       unsigned int& hi, unsigned int& lo) {
    float2 p; p.x = a; p.y = b;
    __hip_bfloat162 h = __float22bfloat162_rn(p);
    unsigned int hu; __builtin_memcpy(&hu, &h, 4);
    float2 r;
    r.x = a - __uint_as_float((hu & 0xffffu) << 16);
    r.y = b - __uint_as_float(hu & 0xffff0000u);
    __hip_bfloat162 l = __float22bfloat162_rn(r);
    unsigned int lu; __builtin_memcpy(&lu, &l, 4);
    hi = hu; lo = lu;
}

// ---------------------------------------------------------------------------
// Prep: split W into MFMA-fragment-ordered bf16 hi/lo.
// Frag (kc, nt, L): e = nt*16 + (L&15), k = kc*32 + (L>>4)*8 .. +7.
// Bit-identical to the round-4 in-loop split (same RNE ops).
// ---------------------------------------------------------------------------
__global__ __launch_bounds__(256) void prep_w(const float* __restrict__ W,
                                              uint4* __restrict__ wsW) {
    const int f   = blockIdx.x * 256 + threadIdx.x;   // 0 .. 46079
    const int kc  = f >> 9;
    const int rem = f & 511;
    const int nt  = rem >> 6;
    const int L   = rem & 63;
    const int e   = nt * 16 + (L & 15);
    const int k   = kc * KC + (L >> 4) * 8;
    const float* p = W + (size_t)e * H_DIM + k;
    const float4 x0 = *(const float4*)p;
    const float4 x1 = *(const float4*)(p + 4);
    uint4 hi, lo;
    split2(x0.x, x0.y, hi.x, lo.x);
    split2(x0.z, x0.w, hi.y, lo.y);
    split2(x1.x, x1.y, hi.z, lo.z);
    split2(x1.z, x1.w, hi.w, lo.w);
    wsW[(size_t)kc * 1024 + nt * 64 + L]       = hi;
    wsW[(size_t)kc * 1024 + 512 + nt * 64 + L] = lo;
}

// ---------------------------------------------------------------------------
// Main (prep path): bf16x3 MFMA GEMM (16x16x32), in-block split-K (2 halves),
// W staged via global_load_lds (width 16) from pre-split frags; A staged via
// register prefetch + 2 split2/thread. Fused bias + top-5 + gap + softmax.
// 512 threads (8 waves), grid 512. LDS 56.5 KB -> 2 blocks/CU.
// ---------------------------------------------------------------------------
__global__ __launch_bounds__(512, 4) void router_main(
    const float* __restrict__ A, const uint4* __restrict__ wsW,
    const float* __restrict__ bias, float* __restrict__ out,
    int* __restrict__ flag_count, int* __restrict__ flag_list)
{
    __shared__ __align__(16) uint2 sAhi[2][2][128];   // [half][m-tile][frag] 4 KB
    __shared__ __align__(16) uint2 sAlo[2][2][128];   //                      4 KB
    __shared__ __align__(16) uint4 sW[2][1024];       // [half][hi:512|lo:512] 32 KB
    __shared__ float sL[MT][129];                     // logits              16.5 KB

    const int tid    = threadIdx.x;
    const int t_base = blockIdx.x * MT;

    const int wave  = tid >> 6;
    const int L     = tid & 63;
    const int whalf = wave >> 2;        // K half this wave computes
    const int wm    = wave & 1;         // m-tile
    const int wn    = (wave >> 1) & 1;  // n-half (4 n-tiles)

    // staging maps
    const int shalf = tid >> 8;         // K half this thread stages (== whalf)
    const int tid_h = tid & 255;
    const int at = tid_h >> 3;          // 0..31 token
    const int ac = tid_h & 7;           // 0..7  k-quad
    const int a_idx = (at >> 4) * 128 + ((((ac >> 1) << 4) | (at & 15)) << 1) + (ac & 1);
    const float* Ag = A + (size_t)(t_base + at) * H_DIM + shalf * KHALF + ac * 4;

    const int wv = (wave & 3);          // wave index within half, 0..3
    const uint4* wsrc = wsW + (size_t)(shalf * NCHUNK_H) * 1024 + (wv * 4) * 64 + L;

    uint2* sAhiF = &sAhi[shalf][0][0];
    uint2* sAloF = &sAlo[shalf][0][0];

    f32x4 acc[4];
#pragma unroll
    for (int i = 0; i < 4; ++i) { f32x4 z = {0.f, 0.f, 0.f, 0.f}; acc[i] = z; }

    float4 av = *(const float4*)Ag;     // A data for iteration 0

    for (int it = 0; it < NCHUNK_H; ++it) {
        // split A for this iteration (av prefetched last iteration)
        uint2 ahp, alp;
        split2(av.x, av.y, ahp.x, alp.x);
        split2(av.z, av.w, ahp.y, alp.y);

        __syncthreads();   // previous iteration's fragment reads complete

        sAhiF[a_idx] = ahp;
        sAloF[a_idx] = alp;

        // async W staging: 4 x 16B per thread, direct global->LDS
        const uint4* wc = wsrc + (size_t)it * 1024;
#pragma unroll
        for (int j = 0; j < 4; ++j) {
            __builtin_amdgcn_global_load_lds(
                (const __attribute__((address_space(1))) void*)(wc + j * 64),
                (__attribute__((address_space(3))) void*)&sW[shalf][(wv * 4 + j) * 64],
                16, 0, 0);
        }

        __syncthreads();   // drains vmcnt: W in LDS, A writes visible

        // prefetch next A chunk (latency hidden under MFMA compute)
        if (it + 1 < NCHUNK_H) av = *(const float4*)(Ag + (it + 1) * KC);

        const bf16x8 ahi = *(const bf16x8*)&sAhi[whalf][wm][L * 2];
        const bf16x8 alo = *(const bf16x8*)&sAlo[whalf][wm][L * 2];
#pragma unroll
        for (int i = 0; i < 4; ++i) {
            const int nt = wn * 4 + i;
            const bf16x8 whi = *(const bf16x8*)&sW[whalf][nt * 64 + L];
            const bf16x8 wlo = *(const bf16x8*)&sW[whalf][512 + nt * 64 + L];
            acc[i] = __builtin_amdgcn_mfma_f32_16x16x32_bf16(ahi, whi, acc[i], 0, 0, 0);
            acc[i] = __builtin_amdgcn_mfma_f32_16x16x32_bf16(ahi, wlo, acc[i], 0, 0, 0);
            acc[i] = __builtin_amdgcn_mfma_f32_16x16x32_bf16(alo, whi, acc[i], 0, 0, 0);
        }
    }

    // epilogue: C/D layout col(expert)=lane&15, row(token)=(lane>>4)*4+reg
    __syncthreads();
    if (whalf == 0) {
#pragma unroll
        for (int i = 0; i < 4; ++i) {
            const int e = wn * 64 + i * 16 + (L & 15);
            const float b = bias[e];
#pragma unroll
            for (int r = 0; r < 4; ++r)
                sL[wm * 16 + (L >> 4) * 4 + r][e] = acc[i][r] + b;
        }
    }
    __syncthreads();
    if (whalf == 1) {
#pragma unroll
        for (int i = 0; i < 4; ++i) {
            const int e = wn * 64 + i * 16 + (L & 15);
#pragma unroll
            for (int r = 0; r < 4; ++r)
                sL[wm * 16 + (L >> 4) * 4 + r][e] += acc[i][r];
        }
    }
    __syncthreads();

    // top-5 scan (stable strict '>') + gap test + softmax
    if (tid < MT) {
        float v0 = -1e30f, v1 = -1e30f, v2 = -1e30f, v3 = -1e30f, v4 = -1e30f;
        int   i0 = 0, i1 = 0, i2 = 0, i3 = 0, i4 = 0;
        for (int e = 0; e < E_EXP; ++e) {
            const float x = sL[tid][e];
            if (x > v4) {
                if (x > v0)      { v4=v3;i4=i3; v3=v2;i3=i2; v2=v1;i2=i1; v1=v0;i1=i0; v0=x;i0=e; }
                else if (x > v1) { v4=v3;i4=i3; v3=v2;i3=i2; v2=v1;i2=i1; v1=x;i1=e; }
                else if (x > v2) { v4=v3;i4=i3; v3=v2;i3=i2; v2=x;i2=e; }
                else if (x > v3) { v4=v3;i4=i3; v3=x;i3=e; }
                else             { v4=x;i4=e; }
            }
        }
        const float g0 = v0 - v1, g1 = v1 - v2, g2 = v2 - v3, g3 = v3 - v4;
        float mg = g0 < g1 ? g0 : g1;
        mg = mg < g2 ? mg : g2;
        mg = mg < g3 ? mg : g3;

        const float e0x = expf(v0 - v0);
        const float e1x = expf(v1 - v0);
        const float e2x = expf(v2 - v0);
        const float e3x = expf(v3 - v0);
        const float s   = e0x + e1x + e2x + e3x;

        const int gt = t_base + tid;
        float* out_scores = out;
        float* out_idx    = out + (size_t)T_TOKENS * TOPK;
        out_scores[gt * 4 + 0] = e0x / s;
        out_scores[gt * 4 + 1] = e1x / s;
        out_scores[gt * 4 + 2] = e2x / s;
        out_scores[gt * 4 + 3] = e3x / s;
        out_idx[gt * 4 + 0] = (float)i0;
        out_idx[gt * 4 + 1] = (float)i1;
        out_idx[gt * 4 + 2] = (float)i2;
        out_idx[gt * 4 + 3] = (float)i3;

        if (mg < EPS_GAP) {
            const int p = atomicAdd(flag_count, 1);
            if (p < T_TOKENS) flag_list[p] = gt;
        }
    }
}

// ---------------------------------------------------------------------------
// Fallback main (ws too small for prep path): round-4 kernel, unchanged.
// ---------------------------------------------------------------------------
__global__ __launch_bounds__(512, 4) void router_main_fb(
    const float* __restrict__ A, const float* __restrict__ W,
    const float* __restrict__ bias, float* __restrict__ out,
    int* __restrict__ flag_count, int* __restrict__ flag_list)
{
    __shared__ __align__(16) uint2 sAhi[2][2][128];
    __shared__ __align__(16) uint2 sAlo[2][2][128];
    __shared__ __align__(16) uint4 sWhi[2][8][64];
    __shared__ __align__(16) uint4 sWlo[2][8][64];
    __shared__ float sL[MT][129];

    const int tid    = threadIdx.x;
    const int t_base = blockIdx.x * MT;
    const int wave  = tid >> 6;
    const int L     = tid & 63;
    const int whalf = wave >> 2;
    const int wm    = wave & 1;
    const int wn    = (wave >> 1) & 1;
    const int shalf = tid >> 8;
    const int tid_h = tid & 255;
    const int at = tid_h >> 3;
    const int ac = tid_h & 7;
    const int a_idx = (at >> 4) * 128 + ((((ac >> 1) << 4) | (at & 15)) << 1) + (ac & 1);
    const float* Ag = A + (size_t)(t_base + at) * H_DIM + shalf * KHALF + ac * 4;
    const int we  = tid_h >> 1;
    const int wq0 = (tid_h & 1) * 2;
    const float* Wg = W + (size_t)we * H_DIM + shalf * KHALF + wq0 * 8;
    const int w_nt = we >> 4;
    const int w_n  = we & 15;

    uint2* sAhiF = &sAhi[shalf][0][0];
    uint2* sAloF = &sAlo[shalf][0][0];

    f32x4 acc[4];
#pragma unroll
    for (int i = 0; i < 4; ++i) { f32x4 z = {0.f, 0.f, 0.f, 0.f}; acc[i] = z; }

    for (int k0 = 0; k0 < KHALF; k0 += KC) {
        const float4 av  = *(const float4*)(Ag + k0);
        const float4 wv0 = *(const float4*)(Wg + k0);
        const float4 wv1 = *(const float4*)(Wg + k0 + 4);
        const float4 wv2 = *(const float4*)(Wg + k0 + 8);
        const float4 wv3 = *(const float4*)(Wg + k0 + 12);

        uint2 ahp, alp;
        split2(av.x, av.y, ahp.x, alp.x);
        split2(av.z, av.w, ahp.y, alp.y);
        uint4 whp0, wlp0, whp1, wlp1;
        split2(wv0.x, wv0.y, whp0.x, wlp0.x);
        split2(wv0.z, wv0.w, whp0.y, wlp0.y);
        split2(wv1.x, wv1.y, whp0.z, wlp0.z);
        split2(wv1.z, wv1.w, whp0.w, wlp0.w);
        split2(wv2.x, wv2.y, whp1.x, wlp1.x);
        split2(wv2.z, wv2.w, whp1.y, wlp1.y);
        split2(wv3.x, wv3.y, whp1.z, wlp1.z);
        split2(wv3.z, wv3.w, whp1.w, wlp1.w);

        __syncthreads();
        sAhiF[a_idx] = ahp;
        sAloF[a_idx] = alp;
        sWhi[shalf][w_nt][((wq0 + 0) << 4) | w_n] = whp0;
        sWhi[shalf][w_nt][((wq0 + 1) << 4) | w_n] = whp1;
        sWlo[shalf][w_nt][((wq0 + 0) << 4) | w_n] = wlp0;
        sWlo[shalf][w_nt][((wq0 + 1) << 4) | w_n] = wlp1;
        __syncthreads();

        const bf16x8 ahi = *(const bf16x8*)&sAhi[whalf][wm][L * 2];
        const bf16x8 alo = *(const bf16x8*)&sAlo[whalf][wm][L * 2];
#pragma unroll
        for (int i = 0; i < 4; ++i) {
            const int nt = wn * 4 + i;
            const bf16x8 whi = *(const bf16x8*)&sWhi[whalf][nt][L];
            const bf16x8 wlo = *(const bf16x8*)&sWlo[whalf][nt][L];
            acc[i] = __builtin_amdgcn_mfma_f32_16x16x32_bf16(ahi, whi, acc[i], 0, 0, 0);
            acc[i] = __builtin_amdgcn_mfma_f32_16x16x32_bf16(ahi, wlo, acc[i], 0, 0, 0);
            acc[i] = __builtin_amdgcn_mfma_f32_16x16x32_bf16(alo, whi, acc[i], 0, 0, 0);
        }
    }

    __syncthreads();
    if (whalf == 0) {
#pragma unroll
        for (int i = 0; i < 4; ++i) {
            const int e = wn * 64 + i * 16 + (L & 15);
            const float b = bias[e];
#pragma unroll
            for (int r = 0; r < 4; ++r)
                sL[wm * 16 + (L >> 4) * 4 + r][e] = acc[i][r] + b;
        }
    }
    __syncthreads();
    if (whalf == 1) {
#pragma unroll
        for (int i = 0; i < 4; ++i) {
            const int e = wn * 64 + i * 16 + (L & 15);
#pragma unroll
            for (int r = 0; r < 4; ++r)
                sL[wm * 16 + (L >> 4) * 4 + r][e] += acc[i][r];
        }
    }
    __syncthreads();

    if (tid < MT) {
        float v0 = -1e30f, v1 = -1e30f, v2 = -1e30f, v3 = -1e30f, v4 = -1e30f;
        int   i0 = 0, i1 = 0, i2 = 0, i3 = 0, i4 = 0;
        for (int e = 0; e < E_EXP; ++e) {
            const float x = sL[tid][e];
            if (x > v4) {
                if (x > v0)      { v4=v3;i4=i3; v3=v2;i3=i2; v2=v1;i2=i1; v1=v0;i1=i0; v0=x;i0=e; }
                else if (x > v1) { v4=v3;i4=i3; v3=v2;i3=i2; v2=v1;i2=i1; v1=x;i1=e; }
                else if (x > v2) { v4=v3;i4=i3; v3=v2;i3=i2; v2=x;i2=e; }
                else if (x > v3) { v4=v3;i4=i3; v3=x;i3=e; }
                else             { v4=x;i4=e; }
            }
        }
        const float g0 = v0 - v1, g1 = v1 - v2, g2 = v2 - v3, g3 = v3 - v4;
        float mg = g0 < g1 ? g0 : g1;
        mg = mg < g2 ? mg : g2;
        mg = mg < g3 ? mg : g3;

        const float e0x = expf(v0 - v0);
        const float e1x = expf(v1 - v0);
        const float e2x = expf(v2 - v0);
        const float e3x = expf(v3 - v0);
        const float s   = e0x + e1x + e2x + e3x;

        const int gt = t_base + tid;
        float* out_scores = out;
        float* out_idx    = out + (size_t)T_TOKENS * TOPK;
        out_scores[gt * 4 + 0] = e0x / s;
        out_scores[gt * 4 + 1] = e1x / s;
        out_scores[gt * 4 + 2] = e2x / s;
        out_scores[gt * 4 + 3] = e3x / s;
        out_idx[gt * 4 + 0] = (float)i0;
        out_idx[gt * 4 + 1] = (float)i1;
        out_idx[gt * 4 + 2] = (float)i2;
        out_idx[gt * 4 + 3] = (float)i3;

        if (mg < EPS_GAP) {
            const int p = atomicAdd(flag_count, 1);
            if (p < T_TOKENS) flag_list[p] = gt;
        }
    }
}

// ---------------------------------------------------------------------------
// Recheck: exact f64 recompute of flagged tokens. Depth-2 software pipeline,
// FULL 32-float chunks (8 x float4 per stage — r5 bug was 16-float stages at
// 32-float stride, skipping half of K). Same s0..s3 bucket order as r3/r4.
// ---------------------------------------------------------------------------
__global__ __launch_bounds__(256) void router_recheck(
    const float* __restrict__ A, const float* __restrict__ W,
    const float* __restrict__ bias, float* __restrict__ out,
    const int* __restrict__ flag_count, const int* __restrict__ flag_list)
{
    __shared__ double sPart[256];
    __shared__ double sLog[E_EXP];

    int count = *flag_count;
    if (count > T_TOKENS) count = T_TOKENS;

    const int tid = threadIdx.x;
    const int e   = tid & (E_EXP - 1);
    const int h   = tid >> 7;          // K half: 0 or 1

    for (int i = blockIdx.x; i < count; i += gridDim.x) {
        const int t = flag_list[i];
        const float* arow = A + (size_t)t * H_DIM + h * KHALF;
        const float* wrow = W + (size_t)e * H_DIM + h * KHALF;

        double s0 = 0.0, s1 = 0.0, s2 = 0.0, s3 = 0.0;
        float4 a[8], w[8];
#pragma unroll
        for (int q = 0; q < 8; ++q) {                    // chunk 0: floats 0..31
            a[q] = *(const float4*)(arow + q * 4);
            w[q] = *(const float4*)(wrow + q * 4);
        }
        for (int it = 0; it < KHALF / 32 - 1; ++it) {    // 44 iterations
            const float* ap = arow + (it + 1) * 32;
            const float* wp = wrow + (it + 1) * 32;
            float4 na[8], nw[8];
#pragma unroll
            for (int q = 0; q < 8; ++q) {
                na[q] = *(const float4*)(ap + q * 4);
                nw[q] = *(const float4*)(wp + q * 4);
            }
#pragma unroll
            for (int q = 0; q < 8; ++q) {
                s0 += (double)a[q].x * (double)w[q].x;
                s1 += (double)a[q].y * (double)w[q].y;
                s2 += (double)a[q].z * (double)w[q].z;
                s3 += (double)a[q].w * (double)w[q].w;
            }
#pragma unroll
            for (int q = 0; q < 8; ++q) { a[q] = na[q]; w[q] = nw[q]; }
        }
#pragma unroll
        for (int q = 0; q < 8; ++q) {                    // chunk 44
            s0 += (double)a[q].x * (double)w[q].x;
            s1 += (double)a[q].y * (double)w[q].y;
            s2 += (double)a[q].z * (double)w[q].z;
            s3 += (double)a[q].w * (double)w[q].w;
        }
        sPart[tid] = (s0 + s1) + (s2 + s3);
        __syncthreads();
        if (h == 0) sLog[e] = sPart[e] + sPart[e + 128] + (double)bias[e];
        __syncthreads();

        if (tid == 0) {
            double v0 = -1e300, v1 = -1e300, v2 = -1e300, v3 = -1e300;
            int    i0 = 0, i1 = 0, i2 = 0, i3 = 0;
            for (int q = 0; q < E_EXP; ++q) {
                const double x = sLog[q];
                if (x > v3) {
                    if (x > v0)      { v3=v2;i3=i2; v2=v1;i2=i1; v1=v0;i1=i0; v0=x;i0=q; }
                    else if (x > v1) { v3=v2;i3=i2; v2=v1;i2=i1; v1=x;i1=q; }
                    else if (x > v2) { v3=v2;i3=i2; v2=x;i2=q; }
                    else             { v3=x;i3=q; }
                }
            }
            const double e0x = exp(v0 - v0);
            const double e1x = exp(v1 - v0);
            const double e2x = exp(v2 - v0);
            const double e3x = exp(v3 - v0);
            const double s   = e0x + e1x + e2x + e3x;
            float* out_scores = out;
            float* out_idx    = out + (size_t)T_TOKENS * TOPK;
            out_scores[t * 4 + 0] = (float)(e0x / s);
            out_scores[t * 4 + 1] = (float)(e1x / s);
            out_scores[t * 4 + 2] = (float)(e2x / s);
            out_scores[t * 4 + 3] = (float)(e3x / s);
            out_idx[t * 4 + 0] = (float)i0;
            out_idx[t * 4 + 1] = (float)i1;
            out_idx[t * 4 + 2] = (float)i2;
            out_idx[t * 4 + 3] = (float)i3;
        }
        __syncthreads();
    }
}

extern "C" void kernel_launch(void* const* d_in, const int* in_sizes, int n_in,
                              void* d_out, int out_size, void* d_ws, size_t ws_size,
                              hipStream_t stream) {
    const float* A    = (const float*)d_in[0];
    const float* W    = (const float*)d_in[1];
    const float* bias = (const float*)d_in[2];
    float* out = (float*)d_out;

    if (ws_size >= (size_t)WS_NEED) {
        int*  flag_count = (int*)d_ws;
        int*  flag_list  = (int*)((char*)d_ws + WS_FLOFF);
        uint4* wsW       = (uint4*)((char*)d_ws + WS_WOFF);
        hipMemsetAsync(flag_count, 0, sizeof(int), stream);
        prep_w<<<dim3((NCHUNK * 512) / 256), dim3(256), 0, stream>>>(W, wsW);
        router_main<<<dim3(T_TOKENS / MT), dim3(512), 0, stream>>>(A, wsW, bias, out,
                                                                   flag_count, flag_list);
        router_recheck<<<dim3(512), dim3(256), 0, stream>>>(A, W, bias, out,
                                                            flag_count, flag_list);
    } else {
        int* flag_count = (int*)d_ws;
        int* flag_list  = (int*)d_ws + 1;
        hipMemsetAsync(flag_count, 0, sizeof(int), stream);
        router_main_fb<<<dim3(T_TOKENS / MT), dim3(512), 0, stream>>>(A, W, bias, out,
                                                                      flag_count, flag_list);
        router_recheck<<<dim3(512), dim3(256), 0, stream>>>(A, W, bias, out,
                                                            flag_count, flag_list);
    }
}